// Round 12
// baseline (999.261 us; speedup 1.0000x reference)
//
#include <hip/hip_runtime.h>
#include <cfloat>
#include <climits>
#include <math.h>

#define HD   768
#define MSW  10
#define WFK  20
#define DD   2324    // 3*768+20
#define K2   50
#define NEGF (-1e30f)

// MFMA geometry
#define KPAD 2432          // 19*128, >= DD
#define KAW  4864          // 2*KPAD  (K-concat of [cur | att] for the gate GEMM)
#define MPAD 896           // 7 * 128 (>= m=819)
#define NPAD 2432          // 19 * 128 (>= DD)

typedef __attribute__((ext_vector_type(8))) short    s8b;
typedef __attribute__((ext_vector_type(8))) unsigned short u16x8;
typedef __attribute__((ext_vector_type(4))) float    f32x4;

__device__ inline unsigned short f2bf(float f){
  unsigned u = __float_as_uint(f);
  unsigned r = (u + 0x7FFFu + ((u >> 16) & 1u)) >> 16;   // RNE
  return (unsigned short)r;
}
__device__ inline float bf2f(unsigned short h){
  return __uint_as_float(((unsigned)h) << 16);
}

// ---------------- per-token projections: alphas, p1,p2,p3 -------------------
__global__ void row_proj(const float* __restrict__ seq, const float* __restrict__ Wa,
                         const float* __restrict__ ba, const float* __restrict__ Wm,
                         float* alphas, float* p1, float* p2, float* p3, int W){
  int w = blockIdx.x; int tid = threadIdx.x;
  const float* row = seq + (size_t)w * HD;
  float s0=0.f, s1=0.f, s2=0.f, s3=0.f;
  for(int h=tid; h<HD; h+=256){
    float x = row[h];
    s0 += x * Wa[h];
    s1 += x * Wm[h];
    s2 += x * Wm[HD + h];
    s3 += x * Wm[2*HD + h];
  }
  __shared__ float r0[256], r1[256], r2[256], r3[256];
  r0[tid]=s0; r1[tid]=s1; r2[tid]=s2; r3[tid]=s3;
  __syncthreads();
  for(int st=128; st>0; st>>=1){
    if(tid<st){ r0[tid]+=r0[tid+st]; r1[tid]+=r1[tid+st]; r2[tid]+=r2[tid+st]; r3[tid]+=r3[tid+st]; }
    __syncthreads();
  }
  if(tid==0){ alphas[w]=r0[0]+ba[0]; p1[w]=r1[0]; p2[w]=r2[0]; p3[w]=r3[0]; }
}

// ---------------- mention scoring per candidate -----------------------------
__global__ void mention_kernel(const float* __restrict__ alphas, const float* __restrict__ p1,
                               const float* __restrict__ p2, const float* __restrict__ p3,
                               const float* __restrict__ wfeat, const float* __restrict__ Wm,
                               const float* __restrict__ bm,
                               const int* __restrict__ smap, const int* __restrict__ gs,
                               const int* __restrict__ ge, const int* __restrict__ cid, int G,
                               float* mscore, float* mmask, int* ccl, int W){
  int c = blockIdx.x*blockDim.x + threadIdx.x;
  int C = W * MSW;
  if(c >= C) return;
  int s = c / MSW, r = c - s*MSW;
  int e = s + r; int ec = min(e, W-1);
  int L = ec - s;
  bool valid = (e < W) && (smap[s] == smap[ec]);
  float maxa = -FLT_MAX;
  for(int j=0;j<=L;j++) maxa = fmaxf(maxa, alphas[s+j]);
  float sum=0.f, sdot=0.f;
  for(int j=0;j<=L;j++){ float ee = expf(alphas[s+j]-maxa); sum += ee; sdot += ee*p3[s+j]; }
  sdot /= sum;
  float wp=0.f;
  for(int f=0; f<WFK; f++) wp += wfeat[L*WFK+f] * Wm[3*HD+f];
  float ms = p1[s] + p2[ec] + sdot + wp + bm[0];
  mscore[c] = ms;
  mmask[c]  = valid ? ms : NEGF;
  int cc = 0;
  for(int g=0; g<G; g++) if(s==gs[g] && ec==ge[g]) cc += cid[g];
  ccl[c] = cc;
}

// ---------------- single-block exact top-m radix select ---------------------
__device__ inline unsigned fkey(float f){
  unsigned b = __float_as_uint(f);
  return (b & 0x80000000u) ? ~b : (b | 0x80000000u);
}

__global__ __launch_bounds__(1024)
void select_kernel(const float* __restrict__ mmask, const float* __restrict__ mscore,
                   const int* __restrict__ ccl, int m, int C, int W,
                   int* top_idx, float* tscore, int* tclust,
                   float* out_ts, float* out_te){
  const int T = 1024;
  int tid = threadIdx.x;
  int chunk = (C + T - 1)/T;
  int lo = tid*chunk, hi = min(lo+chunk, C);
  int n = hi - lo; if(n < 0) n = 0;
  unsigned kb[32];
  for(int t=0;t<n;t++) kb[t] = fkey(mmask[lo+t]);

  __shared__ unsigned s_hist[256];
  __shared__ unsigned s_scan[1024];
  __shared__ unsigned s_pref;
  __shared__ int s_rem;
  if(tid==0){ s_pref=0u; s_rem=m; }
  __syncthreads();

  for(int b=3;b>=0;b--){
    if(tid<256) s_hist[tid]=0u;
    __syncthreads();
    unsigned pref = s_pref;
    unsigned msk = (b==3)?0u:(0xFFFFFFFFu << ((b+1)*8));
    for(int t=0;t<n;t++){
      unsigned u = kb[t];
      if((u & msk)==pref) atomicAdd(&s_hist[(u>>(b*8))&0xFFu], 1u);
    }
    __syncthreads();
    if(tid==0){
      int rem = s_rem; unsigned acc=0u; int bin;
      for(bin=255;bin>=1;bin--){
        unsigned h = s_hist[bin];
        if(acc + h >= (unsigned)rem) break;
        acc += h;
      }
      if(bin < 0) bin = 0;
      s_pref = pref | ((unsigned)bin << (b*8));
      s_rem = rem - (int)acc;
    }
    __syncthreads();
  }
  unsigned Tk = s_pref;
  int need = s_rem;

  unsigned nG=0, nE=0;
  for(int t=0;t<n;t++){ unsigned u=kb[t]; nG += (u>Tk)?1u:0u; nE += (u==Tk)?1u:0u; }

  s_scan[tid]=nE; __syncthreads();
  for(int off=1; off<T; off<<=1){
    unsigned x = (tid>=off)? s_scan[tid-off]:0u; __syncthreads();
    s_scan[tid]+=x; __syncthreads();
  }
  unsigned eqBase = s_scan[tid]-nE;
  __syncthreads();

  int takeLeft = need - (int)eqBase;
  int take = takeLeft<0?0:(takeLeft>(int)nE?(int)nE:takeLeft);
  unsigned selCnt = nG + (unsigned)take;

  s_scan[tid]=selCnt; __syncthreads();
  for(int off=1; off<T; off<<=1){
    unsigned x = (tid>=off)? s_scan[tid-off]:0u; __syncthreads();
    s_scan[tid]+=x; __syncthreads();
  }
  unsigned posBase = s_scan[tid]-selCnt;

  int pos = (int)posBase; int eq = (int)eqBase;
  for(int t=0;t<n;t++){
    unsigned u = kb[t];
    bool sel = false;
    if(u>Tk) sel=true;
    else if(u==Tk){ if(eq<need) sel=true; eq++; }
    if(sel){
      int c = lo+t;
      top_idx[pos] = c;
      int s = c/MSW, r = c - s*MSW; int e = min(s + r, W-1);
      tscore[pos] = mscore[c];
      tclust[pos] = ccl[c];
      out_ts[pos] = (float)s;
      out_te[pos] = (float)e;
      pos++;
    }
  }
}

// ---------------- build top_rep (m x D) -------------------------------------
__global__ void build_rep(const float* __restrict__ seq, const float* __restrict__ alphas,
                          const float* __restrict__ wfeat, const int* __restrict__ top_idx,
                          float* rep, int W){
  int i = blockIdx.x; int tid = threadIdx.x;
  int c = top_idx[i];
  int s = c/MSW, r = c - s*MSW; int ec = min(s + r, W-1); int L = ec - s;
  float wv[MSW];
  float maxa = -FLT_MAX;
  for(int j=0;j<=L;j++) maxa = fmaxf(maxa, alphas[s+j]);
  float sum = 0.f;
  for(int j=0;j<=L;j++){ wv[j] = expf(alphas[s+j]-maxa); sum += wv[j]; }
  float inv = 1.f/sum;
  float* o = rep + (size_t)i*DD;
  for(int d=tid; d<HD; d+=256){
    o[d]      = seq[(size_t)s*HD + d];
    o[HD+d]   = seq[(size_t)ec*HD + d];
    float sp = 0.f;
    for(int j=0;j<=L;j++) sp += wv[j]*seq[(size_t)(s+j)*HD + d];
    o[2*HD+d] = sp*inv;
  }
  for(int f=tid; f<WFK; f+=256) o[3*HD+f] = wfeat[L*WFK+f];
}

// ---------------- zero helper -----------------------------------------------
__global__ void zero_buf(float* __restrict__ p, int n){
  int i = blockIdx.x*256 + threadIdx.x;
  if(i < n) p[i] = 0.f;
}

// ---------------- split-bf16 conversions ------------------------------------
__global__ void conv_split(const float* __restrict__ src, int rows, int cols,
                           unsigned short* __restrict__ hi, unsigned short* __restrict__ lo){
  int idx = blockIdx.x*256 + threadIdx.x;
  if(idx >= MPAD*KPAD) return;
  int row = idx / KPAD, col = idx - row*KPAD;
  float v = (row < rows && col < cols) ? src[(size_t)row*cols + col] : 0.f;
  unsigned short h = f2bf(v);
  hi[idx] = h;
  lo[idx] = f2bf(v - bf2f(h));
}

// Wc (DD x DD) -> transposed hi/lo planes (NPAD x KPAD): Wt[n][k] = Wc[k][n]
__global__ void conv_split_wcT(const float* __restrict__ Wc,
                               unsigned short* __restrict__ WtH, unsigned short* __restrict__ WtL){
  int n  = blockIdx.y*64 + threadIdx.x;
  int k8 = blockIdx.x*8;
  u16x8 vh, vl;
  #pragma unroll
  for(int j=0;j<8;j++){
    int k = k8 + j;
    float f = (n < DD && k < DD) ? Wc[(size_t)k*DD + n] : 0.f;
    unsigned short h = f2bf(f);
    vh[j] = h;
    vl[j] = f2bf(f - bf2f(h));
  }
  *(u16x8*)(WtH + (size_t)n*KPAD + k8) = vh;
  *(u16x8*)(WtL + (size_t)n*KPAD + k8) = vl;
}

// cur -> CurBf (bf16) and Xbf = bf16(cur * w3row)  (both MPAD x KPAD)
__global__ void conv_slow_ops(const float* __restrict__ cur, const float* __restrict__ Wa3,
                              unsigned short* __restrict__ CurBf, unsigned short* __restrict__ Xbf,
                              int m){
  int idx = blockIdx.x*256 + threadIdx.x;
  if(idx >= MPAD*KPAD) return;
  int row = idx / KPAD, col = idx - row*KPAD;
  float v = 0.f, w = 0.f;
  if(row < m && col < DD){ v = cur[(size_t)row*DD + col]; w = Wa3[2*DD + col]; }
  CurBf[idx] = f2bf(v);
  Xbf[idx]   = f2bf(v * w);
}

// ---------------- split-bf16 3-term MFMA GEMM, split-K (BK=32, atomic out) --
// LDS: 4 planes x 2 bufs x 128x40 shorts = 81920 B -> 2 blocks/CU
__global__ __launch_bounds__(256)
void gemm_split3_sk(const unsigned short* __restrict__ Ah, const unsigned short* __restrict__ Al,
                    const unsigned short* __restrict__ Bth, const unsigned short* __restrict__ Btl,
                    float* __restrict__ C, int M, int N, int ldc){
  __shared__ __align__(16) unsigned short sAh[2][128*40];
  __shared__ __align__(16) unsigned short sAl[2][128*40];
  __shared__ __align__(16) unsigned short sBh[2][128*40];
  __shared__ __align__(16) unsigned short sBl[2][128*40];
  int t = threadIdx.x;
  int row0 = blockIdx.y*128, col0 = blockIdx.x*128;
  int tiles = KPAD/32;
  int per = (tiles + gridDim.z - 1)/gridDim.z;
  int tb = min((int)blockIdx.z*per, tiles), te = min(tb + per, tiles);
  int kbeg = tb*32, kend = te*32;
  if(kbeg >= kend) return;
  int r4 = t>>2, seg = t&3;
  int lane = t&63, w = t>>6;
  int wr = (w>>1)*64, wc = (w&1)*64;
  int quad = lane>>4, l15 = lane&15;
  f32x4 acc[4][4];
  #pragma unroll
  for(int mi=0;mi<4;mi++)
    #pragma unroll
    for(int ni=0;ni<4;ni++) acc[mi][ni] = (f32x4){0.f,0.f,0.f,0.f};

  const unsigned short* Ah0 = Ah  + (size_t)(row0+r4   )*KPAD + kbeg + seg*8;
  const unsigned short* Ah1 = Ah  + (size_t)(row0+r4+64)*KPAD + kbeg + seg*8;
  const unsigned short* Al0 = Al  + (size_t)(row0+r4   )*KPAD + kbeg + seg*8;
  const unsigned short* Al1 = Al  + (size_t)(row0+r4+64)*KPAD + kbeg + seg*8;
  const unsigned short* Bh0 = Bth + (size_t)(col0+r4   )*KPAD + kbeg + seg*8;
  const unsigned short* Bh1 = Bth + (size_t)(col0+r4+64)*KPAD + kbeg + seg*8;
  const unsigned short* Bl0 = Btl + (size_t)(col0+r4   )*KPAD + kbeg + seg*8;
  const unsigned short* Bl1 = Btl + (size_t)(col0+r4+64)*KPAD + kbeg + seg*8;
  const int wlo = r4*40 + seg*8, whi = (r4+64)*40 + seg*8;

  u16x8 ah0,ah1,al0,al1,bh0,bh1,bl0,bl1;
  ah0=*(const u16x8*)Ah0; ah1=*(const u16x8*)Ah1;
  al0=*(const u16x8*)Al0; al1=*(const u16x8*)Al1;
  bh0=*(const u16x8*)Bh0; bh1=*(const u16x8*)Bh1;
  bl0=*(const u16x8*)Bl0; bl1=*(const u16x8*)Bl1;
  *(u16x8*)&sAh[0][wlo]=ah0; *(u16x8*)&sAh[0][whi]=ah1;
  *(u16x8*)&sAl[0][wlo]=al0; *(u16x8*)&sAl[0][whi]=al1;
  *(u16x8*)&sBh[0][wlo]=bh0; *(u16x8*)&sBh[0][whi]=bh1;
  *(u16x8*)&sBl[0][wlo]=bl0; *(u16x8*)&sBl[0][whi]=bl1;
  __syncthreads();
  int buf = 0;
  for(int k0=kbeg; k0<kend; k0+=32){
    int nk = k0 + 32;
    if(nk < kend){
      int off = nk - kbeg;
      ah0=*(const u16x8*)(Ah0+off); ah1=*(const u16x8*)(Ah1+off);
      al0=*(const u16x8*)(Al0+off); al1=*(const u16x8*)(Al1+off);
      bh0=*(const u16x8*)(Bh0+off); bh1=*(const u16x8*)(Bh1+off);
      bl0=*(const u16x8*)(Bl0+off); bl1=*(const u16x8*)(Bl1+off);
    }
    s8b fah[4], fal[4], fbh[4], fbl[4];
    #pragma unroll
    for(int mi=0;mi<4;mi++){
      fah[mi] = *(const s8b*)&sAh[buf][(wr+mi*16+l15)*40 + quad*8];
      fal[mi] = *(const s8b*)&sAl[buf][(wr+mi*16+l15)*40 + quad*8];
    }
    #pragma unroll
    for(int ni=0;ni<4;ni++){
      fbh[ni] = *(const s8b*)&sBh[buf][(wc+ni*16+l15)*40 + quad*8];
      fbl[ni] = *(const s8b*)&sBl[buf][(wc+ni*16+l15)*40 + quad*8];
    }
    #pragma unroll
    for(int mi=0;mi<4;mi++)
      #pragma unroll
      for(int ni=0;ni<4;ni++){
        acc[mi][ni] = __builtin_amdgcn_mfma_f32_16x16x32_bf16(fah[mi], fbh[ni], acc[mi][ni], 0,0,0);
        acc[mi][ni] = __builtin_amdgcn_mfma_f32_16x16x32_bf16(fah[mi], fbl[ni], acc[mi][ni], 0,0,0);
        acc[mi][ni] = __builtin_amdgcn_mfma_f32_16x16x32_bf16(fal[mi], fbh[ni], acc[mi][ni], 0,0,0);
      }
    if(nk < kend){
      int nb = buf^1;
      *(u16x8*)&sAh[nb][wlo]=ah0; *(u16x8*)&sAh[nb][whi]=ah1;
      *(u16x8*)&sAl[nb][wlo]=al0; *(u16x8*)&sAl[nb][whi]=al1;
      *(u16x8*)&sBh[nb][wlo]=bh0; *(u16x8*)&sBh[nb][whi]=bh1;
      *(u16x8*)&sBl[nb][wlo]=bl0; *(u16x8*)&sBl[nb][whi]=bl1;
      __syncthreads();
      buf = nb;
    }
  }

  #pragma unroll
  for(int ni=0;ni<4;ni++){
    int gn = col0 + wc + ni*16 + l15;
    if(gn >= N) continue;
    #pragma unroll
    for(int mi=0;mi<4;mi++){
      #pragma unroll
      for(int rg=0;rg<4;rg++){
        int gr = row0 + wr + mi*16 + quad*4 + rg;
        if(gr >= M) continue;
        atomicAdd(&C[(size_t)gr*ldc + gn], acc[mi][ni][rg]);
      }
    }
  }
}

// ---------------- plain bf16 MFMA GEMM, split-K (BK=32, atomic out) ---------
// LDS: 2 mats x 2 bufs x 128x40 shorts = 40960 B -> 4 blocks/CU
__global__ __launch_bounds__(256)
void gemm_plain1_sk(const unsigned short* __restrict__ Ah, const unsigned short* __restrict__ Bth,
                    float* __restrict__ C, int M, int N, int ldc){
  __shared__ __align__(16) unsigned short sA[2][128*40];
  __shared__ __align__(16) unsigned short sB[2][128*40];
  int t = threadIdx.x;
  int row0 = blockIdx.y*128, col0 = blockIdx.x*128;
  int tiles = KPAD/32;
  int per = (tiles + gridDim.z - 1)/gridDim.z;
  int tb = min((int)blockIdx.z*per, tiles), te = min(tb + per, tiles);
  int kbeg = tb*32, kend = te*32;
  if(kbeg >= kend) return;
  int r4 = t>>2, seg = t&3;
  int lane = t&63, w = t>>6;
  int wr = (w>>1)*64, wc = (w&1)*64;
  int quad = lane>>4, l15 = lane&15;
  f32x4 acc[4][4];
  #pragma unroll
  for(int mi=0;mi<4;mi++)
    #pragma unroll
    for(int ni=0;ni<4;ni++) acc[mi][ni] = (f32x4){0.f,0.f,0.f,0.f};

  const unsigned short* Ap0 = Ah  + (size_t)(row0+r4   )*KPAD + kbeg + seg*8;
  const unsigned short* Ap1 = Ah  + (size_t)(row0+r4+64)*KPAD + kbeg + seg*8;
  const unsigned short* Bp0 = Bth + (size_t)(col0+r4   )*KPAD + kbeg + seg*8;
  const unsigned short* Bp1 = Bth + (size_t)(col0+r4+64)*KPAD + kbeg + seg*8;
  const int wlo = r4*40 + seg*8, whi = (r4+64)*40 + seg*8;

  u16x8 a0,a1,b0,b1;
  a0=*(const u16x8*)Ap0; a1=*(const u16x8*)Ap1;
  b0=*(const u16x8*)Bp0; b1=*(const u16x8*)Bp1;
  *(u16x8*)&sA[0][wlo]=a0; *(u16x8*)&sA[0][whi]=a1;
  *(u16x8*)&sB[0][wlo]=b0; *(u16x8*)&sB[0][whi]=b1;
  __syncthreads();
  int buf = 0;
  for(int k0=kbeg; k0<kend; k0+=32){
    int nk = k0 + 32;
    if(nk < kend){
      int off = nk - kbeg;
      a0=*(const u16x8*)(Ap0+off); a1=*(const u16x8*)(Ap1+off);
      b0=*(const u16x8*)(Bp0+off); b1=*(const u16x8*)(Bp1+off);
    }
    s8b fa[4], fb[4];
    #pragma unroll
    for(int mi=0;mi<4;mi++) fa[mi] = *(const s8b*)&sA[buf][(wr+mi*16+l15)*40 + quad*8];
    #pragma unroll
    for(int ni=0;ni<4;ni++) fb[ni] = *(const s8b*)&sB[buf][(wc+ni*16+l15)*40 + quad*8];
    #pragma unroll
    for(int mi=0;mi<4;mi++)
      #pragma unroll
      for(int ni=0;ni<4;ni++)
        acc[mi][ni] = __builtin_amdgcn_mfma_f32_16x16x32_bf16(fa[mi], fb[ni], acc[mi][ni], 0,0,0);
    if(nk < kend){
      int nb = buf^1;
      *(u16x8*)&sA[nb][wlo]=a0; *(u16x8*)&sA[nb][whi]=a1;
      *(u16x8*)&sB[nb][wlo]=b0; *(u16x8*)&sB[nb][whi]=b1;
      __syncthreads();
      buf = nb;
    }
  }

  #pragma unroll
  for(int ni=0;ni<4;ni++){
    int gn = col0 + wc + ni*16 + l15;
    if(gn >= N) continue;
    #pragma unroll
    for(int mi=0;mi<4;mi++){
      #pragma unroll
      for(int rg=0;rg<4;rg++){
        int gr = row0 + wr + mi*16 + quad*4 + rg;
        if(gr >= M) continue;
        atomicAdd(&C[(size_t)gr*ldc + gn], acc[mi][ni][rg]);
      }
    }
  }
}

// ---------------- per-row top-50 antecedents (1 wave / row) -----------------
__global__ void topante_kernel(const float* __restrict__ tscore, const float* __restrict__ bilin,
                               int m, int* ante, float* tafast, float* out_ante){
  int i = blockIdx.x; int lane = threadIdx.x;
  __shared__ float vals[832];
  float tsi = tscore[i];
  for(int j=lane; j<m; j+=64){
    float f = tsi + tscore[j];
    f += (j < i) ? 0.f : NEGF;
    f += bilin[(size_t)i*m + j];
    vals[j] = f;
  }
  __syncthreads();
  for(int t=0; t<K2; t++){
    float bv = -FLT_MAX; int bi = m;
    for(int j=lane; j<m; j+=64){
      float v = vals[j];
      if(v > bv){ bv = v; bi = j; }     // ascending scan keeps lowest j on ties
    }
    #pragma unroll
    for(int off=32; off>0; off>>=1){
      float ov = __shfl_down(bv, off);
      int   oi = __shfl_down(bi, off);
      if(ov > bv || (ov == bv && oi < bi)){ bv = ov; bi = oi; }
    }
    bi = __shfl(bi, 0); bv = __shfl(bv, 0);
    if(lane==0){
      ante[(size_t)i*K2 + t]   = bi;
      tafast[(size_t)i*K2 + t] = bv;
      out_ante[(size_t)i*K2+t] = (float)bi;
      vals[bi] = -FLT_MAX;
    }
    __syncthreads();
  }
}

// ---------------- depth loop pieces -----------------------------------------
__global__ void uv_kernel(const float* __restrict__ reps, const float* __restrict__ Wa3,
                          float* u, float* v, int m){
  int i = blockIdx.x; int tid = threadIdx.x;
  const float* rp = reps + (size_t)i*DD;
  float s1=0.f, s2=0.f;
  for(int d=tid; d<DD; d+=256){ float x = rp[d]; s1 += x*Wa3[d]; s2 += x*Wa3[DD+d]; }
  __shared__ float r1[256], r2[256];
  r1[tid]=s1; r2[tid]=s2; __syncthreads();
  for(int st=128; st>0; st>>=1){
    if(tid<st){ r1[tid]+=r1[tid+st]; r2[tid]+=r2[tid+st]; }
    __syncthreads();
  }
  if(tid==0){ u[i]=r1[0]; v[i]=r2[0]; }
}

// sc[p] = tafast[p] + u[i] + v[j] + P[i][j] + ba
__global__ void slow_gather(const float* __restrict__ P, const float* __restrict__ u,
                            const float* __restrict__ v, const int* __restrict__ ante,
                            const float* __restrict__ tafast, const float* __restrict__ ba,
                            float* sc, int m){
  int p = blockIdx.x*256 + threadIdx.x;
  if(p >= m*K2) return;
  int i = p / K2; int j = ante[p];
  sc[p] = tafast[p] + u[i] + v[j] + P[(size_t)i*m + j] + ba[0];
}

__global__ void attend_kernel(const float* __restrict__ reps, const float* __restrict__ sc,
                              const int* __restrict__ ante, float* att, int m){
  int i = blockIdx.x; int tid = threadIdx.x;
  __shared__ float wts[K2+1];
  __shared__ float scs[K2];
  __shared__ int   js[K2];
  if(tid < K2){ scs[tid] = sc[(size_t)i*K2 + tid]; js[tid] = ante[(size_t)i*K2 + tid]; }
  __syncthreads();
  if(tid==0){
    float mx = 0.f;
    for(int t=0;t<K2;t++) mx = fmaxf(mx, scs[t]);
    float sum = expf(0.f - mx); wts[0] = sum;
    for(int t=0;t<K2;t++){ float e = expf(scs[t]-mx); wts[t+1]=e; sum += e; }
    float inv = 1.f/sum;
    for(int t=0;t<=K2;t++) wts[t] *= inv;
  }
  __syncthreads();
  const float* ri_ = reps + (size_t)i*DD;
  for(int d=tid; d<DD; d+=256){
    float a = wts[0]*ri_[d];
    for(int t=0;t<K2;t++) a += wts[t+1]*reps[(size_t)js[t]*DD + d];
    att[(size_t)i*DD + d] = a;
  }
}

// ---------------- bf16 conversion for the fused gate GEMM -------------------
__global__ void conv_acat(const float* __restrict__ cur, const float* __restrict__ att,
                          unsigned short* __restrict__ A, int m){
  int idx = blockIdx.x*256 + threadIdx.x;
  if(idx >= MPAD*KAW) return;
  int row = idx / KAW, col = idx - row*KAW;
  float v = 0.f;
  if(row < m){
    if(col < DD) v = cur[(size_t)row*DD + col];
    else if(col >= KPAD && col < KPAD + DD) v = att[(size_t)row*DD + (col - KPAD)];
  }
  A[idx] = f2bf(v);
}

// Bt_cat (NPAD x KAW): Bt[n][s*KPAD+k] = Wf[s*DD+k][n], zero-padded
__global__ void conv_wf(const float* __restrict__ Wf, unsigned short* __restrict__ Bt){
  int n  = blockIdx.y*64 + threadIdx.x;
  int k8 = blockIdx.x*8;
  int s  = (k8 >= KPAD) ? 1 : 0;
  int kk = k8 - s*KPAD;
  u16x8 v;
  #pragma unroll
  for(int j=0;j<8;j++){
    int k = kk + j;
    float f = (n < DD && k < DD) ? Wf[(size_t)(s*DD + k)*DD + n] : 0.f;
    v[j] = f2bf(f);
  }
  *(u16x8*)(Bt + (size_t)n*KAW + k8) = v;
}

// ---------------- gate GEMM, split-K (BK=32, atomic out) --------------------
// accumulates pre-activation (no bias) into Pre (= nxt buffer, pre-zeroed)
// LDS 40960 B -> 4 blocks/CU
__global__ __launch_bounds__(256)
void wf_gate_gemm_sk(const unsigned short* __restrict__ Abuf,
                     const unsigned short* __restrict__ Bbuf,
                     float* __restrict__ Pre, int M){
  __shared__ __align__(16) unsigned short As[2][128*40];
  __shared__ __align__(16) unsigned short Bs[2][128*40];
  int t = threadIdx.x;
  int row0 = blockIdx.y*128, col0 = blockIdx.x*128;
  int tiles = KAW/32;
  int per = (tiles + gridDim.z - 1)/gridDim.z;
  int tb = min((int)blockIdx.z*per, tiles), te = min(tb + per, tiles);
  int kbeg = tb*32, kend = te*32;
  if(kbeg >= kend) return;
  int r4 = t>>2, seg = t&3;
  int lane = t&63, w = t>>6;
  int wr = (w>>1)*64, wc = (w&1)*64;
  int quad = lane>>4, l15 = lane&15;
  f32x4 acc[4][4];
  #pragma unroll
  for(int mi=0;mi<4;mi++)
    #pragma unroll
    for(int ni=0;ni<4;ni++) acc[mi][ni] = (f32x4){0.f,0.f,0.f,0.f};

  const unsigned short* Ap0 = Abuf + (size_t)(row0+r4   )*KAW + kbeg + seg*8;
  const unsigned short* Ap1 = Abuf + (size_t)(row0+r4+64)*KAW + kbeg + seg*8;
  const unsigned short* Bp0 = Bbuf + (size_t)(col0+r4   )*KAW + kbeg + seg*8;
  const unsigned short* Bp1 = Bbuf + (size_t)(col0+r4+64)*KAW + kbeg + seg*8;
  const int wlo = r4*40 + seg*8, whi = (r4+64)*40 + seg*8;

  u16x8 a0,a1,b0,b1;
  a0=*(const u16x8*)Ap0; a1=*(const u16x8*)Ap1;
  b0=*(const u16x8*)Bp0; b1=*(const u16x8*)Bp1;
  *(u16x8*)&As[0][wlo]=a0; *(u16x8*)&As[0][whi]=a1;
  *(u16x8*)&Bs[0][wlo]=b0; *(u16x8*)&Bs[0][whi]=b1;
  __syncthreads();
  int buf = 0;
  for(int k0=kbeg; k0<kend; k0+=32){
    int nk = k0 + 32;
    if(nk < kend){
      int off = nk - kbeg;
      a0=*(const u16x8*)(Ap0+off); a1=*(const u16x8*)(Ap1+off);
      b0=*(const u16x8*)(Bp0+off); b1=*(const u16x8*)(Bp1+off);
    }
    s8b fa[4], fb[4];
    #pragma unroll
    for(int mi=0;mi<4;mi++) fa[mi] = *(const s8b*)&As[buf][(wr+mi*16+l15)*40 + quad*8];
    #pragma unroll
    for(int ni=0;ni<4;ni++) fb[ni] = *(const s8b*)&Bs[buf][(wc+ni*16+l15)*40 + quad*8];
    #pragma unroll
    for(int mi=0;mi<4;mi++)
      #pragma unroll
      for(int ni=0;ni<4;ni++)
        acc[mi][ni] = __builtin_amdgcn_mfma_f32_16x16x32_bf16(fa[mi], fb[ni], acc[mi][ni], 0,0,0);
    if(nk < kend){
      int nb = buf^1;
      *(u16x8*)&As[nb][wlo]=a0; *(u16x8*)&As[nb][whi]=a1;
      *(u16x8*)&Bs[nb][wlo]=b0; *(u16x8*)&Bs[nb][whi]=b1;
      __syncthreads();
      buf = nb;
    }
  }

  #pragma unroll
  for(int ni=0;ni<4;ni++){
    int gn = col0 + wc + ni*16 + l15;
    if(gn >= DD) continue;
    #pragma unroll
    for(int mi=0;mi<4;mi++){
      #pragma unroll
      for(int rg=0;rg<4;rg++){
        int gr = row0 + wr + mi*16 + quad*4 + rg;
        if(gr >= M) continue;
        atomicAdd(&Pre[(size_t)gr*DD + gn], acc[mi][ni][rg]);
      }
    }
  }
}

// gate epilogue: nxt holds accumulated pre-activation; apply bias+sigmoid+update
__global__ void gate_update(const float* __restrict__ bfv, const float* __restrict__ att,
                            const float* __restrict__ cur, float* __restrict__ nxt, int total){
  int idx = blockIdx.x*256 + threadIdx.x;
  if(idx >= total) return;
  int col = idx % DD;
  float pre = nxt[idx] + bfv[col];
  float g = 1.f/(1.f + expf(-pre));
  nxt[idx] = g*att[idx] + (1.f - g)*cur[idx];
}

// ---------------- final scores + per-row loss -------------------------------
__global__ void final_loss(const float* __restrict__ sc, const int* __restrict__ ante,
                           const int* __restrict__ tclust, float* out_fs, float* row_loss, int m){
  int i = blockIdx.x*blockDim.x + threadIdx.x;
  if(i >= m) return;
  int tci = tclust[i];
  unsigned long long labm = 0ull;
  bool anyp = false;
  float mx = 0.f;
  float mg = -FLT_MAX;
  for(int t=0;t<K2;t++){
    float v = sc[(size_t)i*K2 + t];
    mx = fmaxf(mx, v);
    int j = ante[(size_t)i*K2 + t];
    bool mk = (j < i);
    int ac = mk ? tclust[j] : -1;
    bool p = (ac == tci) && (tci > 0);
    if(p){ labm |= (1ull << (t+1)); anyp = true; mg = fmaxf(mg, v); }
  }
  if(!anyp){ labm |= 1ull; mg = 0.f; }
  float s1 = expf(0.f - mx);
  float s2 = (labm & 1ull) ? expf(0.f - mg) : 0.f;
  float* o = out_fs + (size_t)i*(K2+1);
  o[0] = 0.f;
  for(int t=0;t<K2;t++){
    float v = sc[(size_t)i*K2 + t];
    o[t+1] = v;
    s1 += expf(v - mx);
    if(labm & (1ull << (t+1))) s2 += expf(v - mg);
  }
  row_loss[i] = (mx + logf(s1)) - (mg + logf(s2));
}

__global__ void loss_sum(const float* __restrict__ row_loss, float* out, int m){
  int tid = threadIdx.x;
  float s = 0.f;
  for(int i=tid; i<m; i+=256) s += row_loss[i];
  __shared__ float red[256];
  red[tid]=s; __syncthreads();
  for(int st=128; st>0; st>>=1){ if(tid<st) red[tid]+=red[tid+st]; __syncthreads(); }
  if(tid==0) out[0] = red[0];
}

// ---------------------------------------------------------------------------
extern "C" void kernel_launch(void* const* d_in, const int* in_sizes, int n_in,
                              void* d_out, int out_size, void* d_ws, size_t ws_size,
                              hipStream_t stream){
  const int W = in_sizes[11];
  const int G = in_sizes[12];
  const int C = W * MSW;
  const int m = (int)(0.4 * (double)W);

  const float* seq   = (const float*)d_in[0];
  const float* Wal   = (const float*)d_in[1];
  const float* bal   = (const float*)d_in[2];
  const float* Wm    = (const float*)d_in[3];
  const float* bm    = (const float*)d_in[4];
  const float* Wc    = (const float*)d_in[5];
  const float* WaA   = (const float*)d_in[6];
  const float* baA   = (const float*)d_in[7];
  const float* Wf    = (const float*)d_in[8];
  const float* bf    = (const float*)d_in[9];
  const float* wfeat = (const float*)d_in[10];
  const int*   smap  = (const int*)d_in[11];
  const int*   gs    = (const int*)d_in[12];
  const int*   ge    = (const int*)d_in[13];
  const int*   cid   = (const int*)d_in[14];
  float* out = (float*)d_out;

  // workspace layout (phase-aliased; peak ~59 MB, proven safe <65 MB)
  char* ws = (char*)d_ws;
  size_t off = 0;
  auto alloc = [&](size_t bytes)->char*{
    char* p = ws + off;
    off += (bytes + 255) & ~(size_t)255;
    return p;
  };
  const size_t PLANE  = (size_t)MPAD*KPAD*2;   // 4.36 MB
  const size_t WPLANE = (size_t)NPAD*KPAD*2;   // 11.83 MB

  float* alphas  = (float*)alloc((size_t)W*4);
  float* p1      = (float*)alloc((size_t)W*4);
  float* p2      = (float*)alloc((size_t)W*4);
  float* p3      = (float*)alloc((size_t)W*4);
  float* mscore  = (float*)alloc((size_t)C*4);
  float* mmask   = (float*)alloc((size_t)C*4);
  int*   ccl     = (int*)  alloc((size_t)C*4);
  int*   top_idx = (int*)  alloc((size_t)m*4);
  float* tscore  = (float*)alloc((size_t)m*4);
  int*   tclust  = (int*)  alloc((size_t)m*4);
  float* B1      = (float*)alloc((size_t)m*DD*4);  // top_rep / reps ping
  float* B2      = (float*)alloc((size_t)m*DD*4);  // tmp / reps pong
  float* B3      = (float*)alloc((size_t)m*DD*4);  // attended
  float* bilin   = (float*)alloc((size_t)m*m*4);   // bilin, later P (slow matrix)
  int*   ante    = (int*)  alloc((size_t)m*K2*4);
  float* tafast  = (float*)alloc((size_t)m*K2*4);
  float* uB      = (float*)alloc((size_t)m*4);
  float* vB      = (float*)alloc((size_t)m*4);
  float* scB     = (float*)alloc((size_t)m*K2*4);
  float* rloss   = (float*)alloc((size_t)m*4);
  // regionA (2*PLANE), phase-aliased:
  //   bilinear: RepH | RepL      slow: XbfA | CurBf      gate: Acat (spans both)
  char* regionA = alloc(2*PLANE);
  unsigned short* RepH  = (unsigned short*)regionA;
  unsigned short* RepL  = (unsigned short*)(regionA + PLANE);
  unsigned short* XbfA  = (unsigned short*)regionA;
  unsigned short* CurBf = (unsigned short*)(regionA + PLANE);
  unsigned short* Acat  = (unsigned short*)regionA;            // MPAD*KAW*2 == 2*PLANE
  // regionB (2*WPLANE), phase-aliased:
  //   gemm1: WtH | WtL   ->  gemm2: A2H | A2L (after gemm1 done)  ->  depth: BtWf
  char* regionB = alloc(2*WPLANE);
  unsigned short* WtH  = (unsigned short*)regionB;
  unsigned short* WtL  = (unsigned short*)(regionB + WPLANE);
  unsigned short* A2H  = (unsigned short*)regionB;
  unsigned short* A2L  = (unsigned short*)(regionB + PLANE);
  unsigned short* BtWf = (unsigned short*)regionB;             // NPAD*KAW*2 == 2*WPLANE

  // output offsets (all float32)
  float* out_ts   = out;
  float* out_te   = out + m;
  float* out_ante = out + 2*m;
  float* out_fs   = out + 2*m + (size_t)m*K2;
  float* out_loss = out + 2*m + (size_t)m*K2 + (size_t)m*(K2+1);

  // 1) per-token projections
  row_proj<<<W, 256, 0, stream>>>(seq, Wal, bal, Wm, alphas, p1, p2, p3, W);
  // 2) candidate mention scores
  mention_kernel<<<(C+255)/256, 256, 0, stream>>>(alphas, p1, p2, p3, wfeat, Wm, bm,
                                                  smap, gs, ge, cid, G,
                                                  mscore, mmask, ccl, W);
  // 3) exact top-m selection + compaction
  select_kernel<<<1, 1024, 0, stream>>>(mmask, mscore, ccl, m, C, W,
                                        top_idx, tscore, tclust, out_ts, out_te);
  // 4) build top_rep into B1
  build_rep<<<m, 256, 0, stream>>>(seq, alphas, wfeat, top_idx, B1, W);
  // 5) bilinear antecedent scores via split-bf16 3-term MFMA (split-K, atomic)
  {
    const int NEL = MPAD*KPAD;
    conv_split<<<(NEL+255)/256, 256, 0, stream>>>(B1, m, DD, RepH, RepL);
    dim3 gw(KPAD/8, NPAD/64);
    conv_split_wcT<<<gw, 64, 0, stream>>>(Wc, WtH, WtL);
    zero_buf<<<(m*DD+255)/256, 256, 0, stream>>>(B2, m*DD);
    dim3 g1(NPAD/128, MPAD/128, 4);     // (19, 7, 4)
    gemm_split3_sk<<<g1, 256, 0, stream>>>(RepH, RepL, WtH, WtL, B2, m, DD, DD);
    conv_split<<<(NEL+255)/256, 256, 0, stream>>>(B2, m, DD, A2H, A2L);
    zero_buf<<<(m*m+255)/256, 256, 0, stream>>>(bilin, m*m);
    dim3 g2(MPAD/128, MPAD/128, 8);     // (7, 7, 8)
    gemm_split3_sk<<<g2, 256, 0, stream>>>(A2H, A2L, RepH, RepL, bilin, m, m, m);
  }
  // 6) per-row top-50 (1 wave per row)
  topante_kernel<<<m, 64, 0, stream>>>(tscore, bilin, m, ante, tafast, out_ante);
  // gate weights -> bf16 transposed (AFTER bilinear GEMMs: regionB alias)
  {
    dim3 g(KAW/8, NPAD/64);
    conv_wf<<<g, 64, 0, stream>>>(Wf, BtWf);
  }

  // 7) DEPTH=2 refinement (loss-path GEMMs: split-K + atomic accumulate)
  float* cur = B1; float* nxt = B2;
  const int NEL = MPAD*KPAD;
  const int total = m * DD;
  for(int depth=0; depth<2; depth++){
    uv_kernel<<<m, 256, 0, stream>>>(cur, WaA, uB, vB, m);
    // slow scores: P = (cur .* w3) @ cur^T  (split-K x8, atomic into zeroed bilin)
    conv_slow_ops<<<(NEL+255)/256, 256, 0, stream>>>(cur, WaA, CurBf, XbfA, m);
    zero_buf<<<(m*m+255)/256, 256, 0, stream>>>(bilin, m*m);
    dim3 gp(MPAD/128, MPAD/128, 8);
    gemm_plain1_sk<<<gp, 256, 0, stream>>>(XbfA, CurBf, bilin, m, m, m);
    slow_gather<<<(m*K2+255)/256, 256, 0, stream>>>(bilin, uB, vB, ante, tafast, baA, scB, m);
    attend_kernel<<<m, 256, 0, stream>>>(cur, scB, ante, B3, m);
    // gate pre-activation accumulates into zeroed nxt; epilogue applied after
    conv_acat<<<(MPAD*KAW+255)/256, 256, 0, stream>>>(cur, B3, Acat, m);
    zero_buf<<<(total+255)/256, 256, 0, stream>>>(nxt, total);
    dim3 gg(NPAD/128, MPAD/128, 8);
    wf_gate_gemm_sk<<<gg, 256, 0, stream>>>(Acat, BtWf, nxt, m);
    gate_update<<<(total+255)/256, 256, 0, stream>>>(bf, B3, cur, nxt, total);
    float* t = cur; cur = nxt; nxt = t;
  }

  // 8) final scores + loss
  final_loss<<<(m+255)/256, 256, 0, stream>>>(scB, ante, tclust, out_fs, rloss, m);
  loss_sum<<<1, 256, 0, stream>>>(rloss, out_loss, m);
}

// Round 13
// 897.540 us; speedup vs baseline: 1.1133x; 1.1133x over previous
//
#include <hip/hip_runtime.h>
#include <cfloat>
#include <climits>
#include <math.h>

#define HD   768
#define MSW  10
#define WFK  20
#define DD   2324    // 3*768+20
#define K2   50
#define NEGF (-1e30f)

// MFMA geometry (K padded to mult of 128 for deep-K tiles)
#define KPAD 2432          // 19*128, >= DD
#define KAW  4864          // 2*KPAD  (K-concat of [cur | att] for the gate GEMM)
#define MPAD 896           // 7 * 128 (>= m=819)
#define NPAD 2432          // 19 * 128 (>= DD)

typedef __attribute__((ext_vector_type(8))) short    s8b;
typedef __attribute__((ext_vector_type(8))) unsigned short u16x8;
typedef __attribute__((ext_vector_type(4))) float    f32x4;

__device__ inline unsigned short f2bf(float f){
  unsigned u = __float_as_uint(f);
  unsigned r = (u + 0x7FFFu + ((u >> 16) & 1u)) >> 16;   // RNE
  return (unsigned short)r;
}
__device__ inline float bf2f(unsigned short h){
  return __uint_as_float(((unsigned)h) << 16);
}

// ---------------- per-token projections: alphas, p1,p2,p3 -------------------
__global__ void row_proj(const float* __restrict__ seq, const float* __restrict__ Wa,
                         const float* __restrict__ ba, const float* __restrict__ Wm,
                         float* alphas, float* p1, float* p2, float* p3, int W){
  int w = blockIdx.x; int tid = threadIdx.x;
  const float* row = seq + (size_t)w * HD;
  float s0=0.f, s1=0.f, s2=0.f, s3=0.f;
  for(int h=tid; h<HD; h+=256){
    float x = row[h];
    s0 += x * Wa[h];
    s1 += x * Wm[h];
    s2 += x * Wm[HD + h];
    s3 += x * Wm[2*HD + h];
  }
  __shared__ float r0[256], r1[256], r2[256], r3[256];
  r0[tid]=s0; r1[tid]=s1; r2[tid]=s2; r3[tid]=s3;
  __syncthreads();
  for(int st=128; st>0; st>>=1){
    if(tid<st){ r0[tid]+=r0[tid+st]; r1[tid]+=r1[tid+st]; r2[tid]+=r2[tid+st]; r3[tid]+=r3[tid+st]; }
    __syncthreads();
  }
  if(tid==0){ alphas[w]=r0[0]+ba[0]; p1[w]=r1[0]; p2[w]=r2[0]; p3[w]=r3[0]; }
}

// ---------------- mention scoring per candidate -----------------------------
__global__ void mention_kernel(const float* __restrict__ alphas, const float* __restrict__ p1,
                               const float* __restrict__ p2, const float* __restrict__ p3,
                               const float* __restrict__ wfeat, const float* __restrict__ Wm,
                               const float* __restrict__ bm,
                               const int* __restrict__ smap, const int* __restrict__ gs,
                               const int* __restrict__ ge, const int* __restrict__ cid, int G,
                               float* mscore, float* mmask, int* ccl, int W){
  int c = blockIdx.x*blockDim.x + threadIdx.x;
  int C = W * MSW;
  if(c >= C) return;
  int s = c / MSW, r = c - s*MSW;
  int e = s + r; int ec = min(e, W-1);
  int L = ec - s;
  bool valid = (e < W) && (smap[s] == smap[ec]);
  float maxa = -FLT_MAX;
  for(int j=0;j<=L;j++) maxa = fmaxf(maxa, alphas[s+j]);
  float sum=0.f, sdot=0.f;
  for(int j=0;j<=L;j++){ float ee = expf(alphas[s+j]-maxa); sum += ee; sdot += ee*p3[s+j]; }
  sdot /= sum;
  float wp=0.f;
  for(int f=0; f<WFK; f++) wp += wfeat[L*WFK+f] * Wm[3*HD+f];
  float ms = p1[s] + p2[ec] + sdot + wp + bm[0];
  mscore[c] = ms;
  mmask[c]  = valid ? ms : NEGF;
  int cc = 0;
  for(int g=0; g<G; g++) if(s==gs[g] && ec==ge[g]) cc += cid[g];
  ccl[c] = cc;
}

// ---------------- single-block exact top-m radix select ---------------------
__device__ inline unsigned fkey(float f){
  unsigned b = __float_as_uint(f);
  return (b & 0x80000000u) ? ~b : (b | 0x80000000u);
}

__global__ __launch_bounds__(1024)
void select_kernel(const float* __restrict__ mmask, const float* __restrict__ mscore,
                   const int* __restrict__ ccl, int m, int C, int W,
                   int* top_idx, float* tscore, int* tclust,
                   float* out_ts, float* out_te){
  const int T = 1024;
  int tid = threadIdx.x;
  int chunk = (C + T - 1)/T;
  int lo = tid*chunk, hi = min(lo+chunk, C);
  int n = hi - lo; if(n < 0) n = 0;
  unsigned kb[32];
  for(int t=0;t<n;t++) kb[t] = fkey(mmask[lo+t]);

  __shared__ unsigned s_hist[256];
  __shared__ unsigned s_scan[1024];
  __shared__ unsigned s_pref;
  __shared__ int s_rem;
  if(tid==0){ s_pref=0u; s_rem=m; }
  __syncthreads();

  for(int b=3;b>=0;b--){
    if(tid<256) s_hist[tid]=0u;
    __syncthreads();
    unsigned pref = s_pref;
    unsigned msk = (b==3)?0u:(0xFFFFFFFFu << ((b+1)*8));
    for(int t=0;t<n;t++){
      unsigned u = kb[t];
      if((u & msk)==pref) atomicAdd(&s_hist[(u>>(b*8))&0xFFu], 1u);
    }
    __syncthreads();
    if(tid==0){
      int rem = s_rem; unsigned acc=0u; int bin;
      for(bin=255;bin>=1;bin--){
        unsigned h = s_hist[bin];
        if(acc + h >= (unsigned)rem) break;
        acc += h;
      }
      if(bin < 0) bin = 0;
      s_pref = pref | ((unsigned)bin << (b*8));
      s_rem = rem - (int)acc;
    }
    __syncthreads();
  }
  unsigned Tk = s_pref;
  int need = s_rem;

  unsigned nG=0, nE=0;
  for(int t=0;t<n;t++){ unsigned u=kb[t]; nG += (u>Tk)?1u:0u; nE += (u==Tk)?1u:0u; }

  s_scan[tid]=nE; __syncthreads();
  for(int off=1; off<T; off<<=1){
    unsigned x = (tid>=off)? s_scan[tid-off]:0u; __syncthreads();
    s_scan[tid]+=x; __syncthreads();
  }
  unsigned eqBase = s_scan[tid]-nE;
  __syncthreads();

  int takeLeft = need - (int)eqBase;
  int take = takeLeft<0?0:(takeLeft>(int)nE?(int)nE:takeLeft);
  unsigned selCnt = nG + (unsigned)take;

  s_scan[tid]=selCnt; __syncthreads();
  for(int off=1; off<T; off<<=1){
    unsigned x = (tid>=off)? s_scan[tid-off]:0u; __syncthreads();
    s_scan[tid]+=x; __syncthreads();
  }
  unsigned posBase = s_scan[tid]-selCnt;

  int pos = (int)posBase; int eq = (int)eqBase;
  for(int t=0;t<n;t++){
    unsigned u = kb[t];
    bool sel = false;
    if(u>Tk) sel=true;
    else if(u==Tk){ if(eq<need) sel=true; eq++; }
    if(sel){
      int c = lo+t;
      top_idx[pos] = c;
      int s = c/MSW, r = c - s*MSW; int e = min(s + r, W-1);
      tscore[pos] = mscore[c];
      tclust[pos] = ccl[c];
      out_ts[pos] = (float)s;
      out_te[pos] = (float)e;
      pos++;
    }
  }
}

// ---------------- build top_rep (m x D) -------------------------------------
__global__ void build_rep(const float* __restrict__ seq, const float* __restrict__ alphas,
                          const float* __restrict__ wfeat, const int* __restrict__ top_idx,
                          float* rep, int W){
  int i = blockIdx.x; int tid = threadIdx.x;
  int c = top_idx[i];
  int s = c/MSW, r = c - s*MSW; int ec = min(s + r, W-1); int L = ec - s;
  float wv[MSW];
  float maxa = -FLT_MAX;
  for(int j=0;j<=L;j++) maxa = fmaxf(maxa, alphas[s+j]);
  float sum = 0.f;
  for(int j=0;j<=L;j++){ wv[j] = expf(alphas[s+j]-maxa); sum += wv[j]; }
  float inv = 1.f/sum;
  float* o = rep + (size_t)i*DD;
  for(int d=tid; d<HD; d+=256){
    o[d]      = seq[(size_t)s*HD + d];
    o[HD+d]   = seq[(size_t)ec*HD + d];
    float sp = 0.f;
    for(int j=0;j<=L;j++) sp += wv[j]*seq[(size_t)(s+j)*HD + d];
    o[2*HD+d] = sp*inv;
  }
  for(int f=tid; f<WFK; f+=256) o[3*HD+f] = wfeat[L*WFK+f];
}

// ---------------- zero helper -----------------------------------------------
__global__ void zero_buf(float* __restrict__ p, int n){
  int i = blockIdx.x*256 + threadIdx.x;
  if(i < n) p[i] = 0.f;
}

// ---------------- split-bf16 conversions ------------------------------------
__global__ void conv_split(const float* __restrict__ src, int rows, int cols,
                           unsigned short* __restrict__ hi, unsigned short* __restrict__ lo){
  int idx = blockIdx.x*256 + threadIdx.x;
  if(idx >= MPAD*KPAD) return;
  int row = idx / KPAD, col = idx - row*KPAD;
  float v = (row < rows && col < cols) ? src[(size_t)row*cols + col] : 0.f;
  unsigned short h = f2bf(v);
  hi[idx] = h;
  lo[idx] = f2bf(v - bf2f(h));
}

// Wc (DD x DD) -> transposed hi/lo planes (NPAD x KPAD): Wt[n][k] = Wc[k][n]
__global__ void conv_split_wcT(const float* __restrict__ Wc,
                               unsigned short* __restrict__ WtH, unsigned short* __restrict__ WtL){
  int n  = blockIdx.y*64 + threadIdx.x;
  int k8 = blockIdx.x*8;
  u16x8 vh, vl;
  #pragma unroll
  for(int j=0;j<8;j++){
    int k = k8 + j;
    float f = (n < DD && k < DD) ? Wc[(size_t)k*DD + n] : 0.f;
    unsigned short h = f2bf(f);
    vh[j] = h;
    vl[j] = f2bf(f - bf2f(h));
  }
  *(u16x8*)(WtH + (size_t)n*KPAD + k8) = vh;
  *(u16x8*)(WtL + (size_t)n*KPAD + k8) = vl;
}

// cur -> CurBf (bf16) and Xbf = bf16(cur * w3row)  (both MPAD x KPAD)
__global__ void conv_slow_ops(const float* __restrict__ cur, const float* __restrict__ Wa3,
                              unsigned short* __restrict__ CurBf, unsigned short* __restrict__ Xbf,
                              int m){
  int idx = blockIdx.x*256 + threadIdx.x;
  if(idx >= MPAD*KPAD) return;
  int row = idx / KPAD, col = idx - row*KPAD;
  float v = 0.f, w = 0.f;
  if(row < m && col < DD){ v = cur[(size_t)row*DD + col]; w = Wa3[2*DD + col]; }
  CurBf[idx] = f2bf(v);
  Xbf[idx]   = f2bf(v * w);
}

// ---------------- split-bf16 3-term MFMA GEMM, split-K (BK=64 dbuf, atomic) -
// LDS: 4 planes x 2 buf x 128x72 shorts = 147456 B (1 block/CU; split-K fills CUs)
__global__ __launch_bounds__(256)
void gemm_split3_sk(const unsigned short* __restrict__ Ah, const unsigned short* __restrict__ Al,
                    const unsigned short* __restrict__ Bth, const unsigned short* __restrict__ Btl,
                    float* __restrict__ C, int M, int N, int ldc){
  __shared__ __align__(16) unsigned short sAh[2][128*72];
  __shared__ __align__(16) unsigned short sAl[2][128*72];
  __shared__ __align__(16) unsigned short sBh[2][128*72];
  __shared__ __align__(16) unsigned short sBl[2][128*72];
  int t = threadIdx.x;
  int row0 = blockIdx.y*128, col0 = blockIdx.x*128;
  int tiles = KPAD/64;                                    // 38
  int per = (tiles + gridDim.z - 1)/gridDim.z;
  int tb = min((int)blockIdx.z*per, tiles), te = min(tb + per, tiles);
  int kbeg = tb*64, kend = te*64;
  if(kbeg >= kend) return;
  int r4 = t>>2, seg = t&3;
  int lane = t&63, w = t>>6;
  int wr = (w>>1)*64, wc = (w&1)*64;
  int quad = lane>>4, l15 = lane&15;
  f32x4 acc[4][4];
  #pragma unroll
  for(int mi=0;mi<4;mi++)
    #pragma unroll
    for(int ni=0;ni<4;ni++) acc[mi][ni] = (f32x4){0.f,0.f,0.f,0.f};

  const unsigned short* Ah0 = Ah  + (size_t)(row0+r4   )*KPAD + kbeg + seg*8;
  const unsigned short* Ah1 = Ah  + (size_t)(row0+r4+64)*KPAD + kbeg + seg*8;
  const unsigned short* Al0 = Al  + (size_t)(row0+r4   )*KPAD + kbeg + seg*8;
  const unsigned short* Al1 = Al  + (size_t)(row0+r4+64)*KPAD + kbeg + seg*8;
  const unsigned short* Bh0 = Bth + (size_t)(col0+r4   )*KPAD + kbeg + seg*8;
  const unsigned short* Bh1 = Bth + (size_t)(col0+r4+64)*KPAD + kbeg + seg*8;
  const unsigned short* Bl0 = Btl + (size_t)(col0+r4   )*KPAD + kbeg + seg*8;
  const unsigned short* Bl1 = Btl + (size_t)(col0+r4+64)*KPAD + kbeg + seg*8;
  const int wlo = r4*72 + seg*8, whi = (r4+64)*72 + seg*8;

  u16x8 pah[2][2], pal[2][2], pbh[2][2], pbl[2][2];
  #pragma unroll
  for(int c=0;c<2;c++){
    pah[0][c]=*(const u16x8*)(Ah0+c*32); pah[1][c]=*(const u16x8*)(Ah1+c*32);
    pal[0][c]=*(const u16x8*)(Al0+c*32); pal[1][c]=*(const u16x8*)(Al1+c*32);
    pbh[0][c]=*(const u16x8*)(Bh0+c*32); pbh[1][c]=*(const u16x8*)(Bh1+c*32);
    pbl[0][c]=*(const u16x8*)(Bl0+c*32); pbl[1][c]=*(const u16x8*)(Bl1+c*32);
  }
  #pragma unroll
  for(int c=0;c<2;c++){
    *(u16x8*)&sAh[0][wlo+c*32]=pah[0][c]; *(u16x8*)&sAh[0][whi+c*32]=pah[1][c];
    *(u16x8*)&sAl[0][wlo+c*32]=pal[0][c]; *(u16x8*)&sAl[0][whi+c*32]=pal[1][c];
    *(u16x8*)&sBh[0][wlo+c*32]=pbh[0][c]; *(u16x8*)&sBh[0][whi+c*32]=pbh[1][c];
    *(u16x8*)&sBl[0][wlo+c*32]=pbl[0][c]; *(u16x8*)&sBl[0][whi+c*32]=pbl[1][c];
  }
  __syncthreads();
  int buf = 0;
  for(int k0=kbeg; k0<kend; k0+=64){
    int nk = k0 + 64;
    if(nk < kend){
      int off = nk - kbeg;
      #pragma unroll
      for(int c=0;c<2;c++){
        pah[0][c]=*(const u16x8*)(Ah0+off+c*32); pah[1][c]=*(const u16x8*)(Ah1+off+c*32);
        pal[0][c]=*(const u16x8*)(Al0+off+c*32); pal[1][c]=*(const u16x8*)(Al1+off+c*32);
        pbh[0][c]=*(const u16x8*)(Bh0+off+c*32); pbh[1][c]=*(const u16x8*)(Bh1+off+c*32);
        pbl[0][c]=*(const u16x8*)(Bl0+off+c*32); pbl[1][c]=*(const u16x8*)(Bl1+off+c*32);
      }
    }
    #pragma unroll
    for(int ks=0;ks<2;ks++){
      s8b fah[4], fal[4], fbh[4], fbl[4];
      #pragma unroll
      for(int mi=0;mi<4;mi++){
        fah[mi] = *(const s8b*)&sAh[buf][(wr+mi*16+l15)*72 + ks*32 + quad*8];
        fal[mi] = *(const s8b*)&sAl[buf][(wr+mi*16+l15)*72 + ks*32 + quad*8];
      }
      #pragma unroll
      for(int ni=0;ni<4;ni++){
        fbh[ni] = *(const s8b*)&sBh[buf][(wc+ni*16+l15)*72 + ks*32 + quad*8];
        fbl[ni] = *(const s8b*)&sBl[buf][(wc+ni*16+l15)*72 + ks*32 + quad*8];
      }
      #pragma unroll
      for(int mi=0;mi<4;mi++)
        #pragma unroll
        for(int ni=0;ni<4;ni++){
          acc[mi][ni] = __builtin_amdgcn_mfma_f32_16x16x32_bf16(fah[mi], fbh[ni], acc[mi][ni], 0,0,0);
          acc[mi][ni] = __builtin_amdgcn_mfma_f32_16x16x32_bf16(fah[mi], fbl[ni], acc[mi][ni], 0,0,0);
          acc[mi][ni] = __builtin_amdgcn_mfma_f32_16x16x32_bf16(fal[mi], fbh[ni], acc[mi][ni], 0,0,0);
        }
    }
    if(nk < kend){
      int nb = buf^1;
      #pragma unroll
      for(int c=0;c<2;c++){
        *(u16x8*)&sAh[nb][wlo+c*32]=pah[0][c]; *(u16x8*)&sAh[nb][whi+c*32]=pah[1][c];
        *(u16x8*)&sAl[nb][wlo+c*32]=pal[0][c]; *(u16x8*)&sAl[nb][whi+c*32]=pal[1][c];
        *(u16x8*)&sBh[nb][wlo+c*32]=pbh[0][c]; *(u16x8*)&sBh[nb][whi+c*32]=pbh[1][c];
        *(u16x8*)&sBl[nb][wlo+c*32]=pbl[0][c]; *(u16x8*)&sBl[nb][whi+c*32]=pbl[1][c];
      }
      __syncthreads();
      buf = nb;
    }
  }

  #pragma unroll
  for(int ni=0;ni<4;ni++){
    int gn = col0 + wc + ni*16 + l15;
    if(gn >= N) continue;
    #pragma unroll
    for(int mi=0;mi<4;mi++){
      #pragma unroll
      for(int rg=0;rg<4;rg++){
        int gr = row0 + wr + mi*16 + quad*4 + rg;
        if(gr >= M) continue;
        atomicAdd(&C[(size_t)gr*ldc + gn], acc[mi][ni][rg]);
      }
    }
  }
}

// ---------------- plain bf16 MFMA GEMM, split-K x4 (BK=64, atomic out) ------
// LDS: 2 mats x 2 bufs x 128x72 shorts = 73728 B -> 2 blocks/CU
__global__ __launch_bounds__(256)
void gemm_plain1_sk(const unsigned short* __restrict__ Ah, const unsigned short* __restrict__ Bth,
                    float* __restrict__ C, int M, int N, int ldc){
  __shared__ __align__(16) unsigned short sA[2][128*72];
  __shared__ __align__(16) unsigned short sB[2][128*72];
  int t = threadIdx.x;
  int row0 = blockIdx.y*128, col0 = blockIdx.x*128;
  int tiles = KPAD/64;                       // 38
  int per = (tiles + 3)/4;                   // 10
  int tb = min((int)blockIdx.z*per, tiles);
  int te = min(tb + per, tiles);
  int kbeg = tb*64, kend = te*64;
  if(kbeg >= kend) return;
  int r4 = t>>2, seg = t&3;
  int lane = t&63, w = t>>6;
  int wr = (w>>1)*64, wc = (w&1)*64;
  int quad = lane>>4, l15 = lane&15;
  f32x4 acc[4][4];
  #pragma unroll
  for(int mi=0;mi<4;mi++)
    #pragma unroll
    for(int ni=0;ni<4;ni++) acc[mi][ni] = (f32x4){0.f,0.f,0.f,0.f};

  const unsigned short* Ap0 = Ah  + (size_t)(row0+r4   )*KPAD + kbeg + seg*8;
  const unsigned short* Ap1 = Ah  + (size_t)(row0+r4+64)*KPAD + kbeg + seg*8;
  const unsigned short* Bp0 = Bth + (size_t)(col0+r4   )*KPAD + kbeg + seg*8;
  const unsigned short* Bp1 = Bth + (size_t)(col0+r4+64)*KPAD + kbeg + seg*8;
  const int wlo = r4*72 + seg*8, whi = (r4+64)*72 + seg*8;

  u16x8 pa[2][2], pb[2][2];
  #pragma unroll
  for(int c=0;c<2;c++){
    pa[0][c]=*(const u16x8*)(Ap0+c*32); pa[1][c]=*(const u16x8*)(Ap1+c*32);
    pb[0][c]=*(const u16x8*)(Bp0+c*32); pb[1][c]=*(const u16x8*)(Bp1+c*32);
  }
  #pragma unroll
  for(int c=0;c<2;c++){
    *(u16x8*)&sA[0][wlo+c*32]=pa[0][c]; *(u16x8*)&sA[0][whi+c*32]=pa[1][c];
    *(u16x8*)&sB[0][wlo+c*32]=pb[0][c]; *(u16x8*)&sB[0][whi+c*32]=pb[1][c];
  }
  __syncthreads();
  int buf = 0;
  for(int k0=kbeg; k0<kend; k0+=64){
    int nk = k0 + 64;
    if(nk < kend){
      int off = nk - kbeg;
      #pragma unroll
      for(int c=0;c<2;c++){
        pa[0][c]=*(const u16x8*)(Ap0+off+c*32); pa[1][c]=*(const u16x8*)(Ap1+off+c*32);
        pb[0][c]=*(const u16x8*)(Bp0+off+c*32); pb[1][c]=*(const u16x8*)(Bp1+off+c*32);
      }
    }
    #pragma unroll
    for(int ks=0;ks<2;ks++){
      s8b fa[4], fb[4];
      #pragma unroll
      for(int mi=0;mi<4;mi++) fa[mi] = *(const s8b*)&sA[buf][(wr+mi*16+l15)*72 + ks*32 + quad*8];
      #pragma unroll
      for(int ni=0;ni<4;ni++) fb[ni] = *(const s8b*)&sB[buf][(wc+ni*16+l15)*72 + ks*32 + quad*8];
      #pragma unroll
      for(int mi=0;mi<4;mi++)
        #pragma unroll
        for(int ni=0;ni<4;ni++)
          acc[mi][ni] = __builtin_amdgcn_mfma_f32_16x16x32_bf16(fa[mi], fb[ni], acc[mi][ni], 0,0,0);
    }
    if(nk < kend){
      int nb = buf^1;
      #pragma unroll
      for(int c=0;c<2;c++){
        *(u16x8*)&sA[nb][wlo+c*32]=pa[0][c]; *(u16x8*)&sA[nb][whi+c*32]=pa[1][c];
        *(u16x8*)&sB[nb][wlo+c*32]=pb[0][c]; *(u16x8*)&sB[nb][whi+c*32]=pb[1][c];
      }
      __syncthreads();
      buf = nb;
    }
  }

  #pragma unroll
  for(int ni=0;ni<4;ni++){
    int gn = col0 + wc + ni*16 + l15;
    if(gn >= N) continue;
    #pragma unroll
    for(int mi=0;mi<4;mi++){
      #pragma unroll
      for(int rg=0;rg<4;rg++){
        int gr = row0 + wr + mi*16 + quad*4 + rg;
        if(gr >= M) continue;
        atomicAdd(&C[(size_t)gr*ldc + gn], acc[mi][ni][rg]);
      }
    }
  }
}

// ---------------- per-row top-50 antecedents (1 wave / row) -----------------
__global__ void topante_kernel(const float* __restrict__ tscore, const float* __restrict__ bilin,
                               int m, int* ante, float* tafast, float* out_ante){
  int i = blockIdx.x; int lane = threadIdx.x;
  __shared__ float vals[832];
  float tsi = tscore[i];
  for(int j=lane; j<m; j+=64){
    float f = tsi + tscore[j];
    f += (j < i) ? 0.f : NEGF;
    f += bilin[(size_t)i*m + j];
    vals[j] = f;
  }
  __syncthreads();
  for(int t=0; t<K2; t++){
    float bv = -FLT_MAX; int bi = m;
    for(int j=lane; j<m; j+=64){
      float v = vals[j];
      if(v > bv){ bv = v; bi = j; }     // ascending scan keeps lowest j on ties
    }
    #pragma unroll
    for(int off=32; off>0; off>>=1){
      float ov = __shfl_down(bv, off);
      int   oi = __shfl_down(bi, off);
      if(ov > bv || (ov == bv && oi < bi)){ bv = ov; bi = oi; }
    }
    bi = __shfl(bi, 0); bv = __shfl(bv, 0);
    if(lane==0){
      ante[(size_t)i*K2 + t]   = bi;
      tafast[(size_t)i*K2 + t] = bv;
      out_ante[(size_t)i*K2+t] = (float)bi;
      vals[bi] = -FLT_MAX;
    }
    __syncthreads();
  }
}

// ---------------- depth loop pieces -----------------------------------------
__global__ void uv_kernel(const float* __restrict__ reps, const float* __restrict__ Wa3,
                          float* u, float* v, int m){
  int i = blockIdx.x; int tid = threadIdx.x;
  const float* rp = reps + (size_t)i*DD;
  float s1=0.f, s2=0.f;
  for(int d=tid; d<DD; d+=256){ float x = rp[d]; s1 += x*Wa3[d]; s2 += x*Wa3[DD+d]; }
  __shared__ float r1[256], r2[256];
  r1[tid]=s1; r2[tid]=s2; __syncthreads();
  for(int st=128; st>0; st>>=1){
    if(tid<st){ r1[tid]+=r1[tid+st]; r2[tid]+=r2[tid+st]; }
    __syncthreads();
  }
  if(tid==0){ u[i]=r1[0]; v[i]=r2[0]; }
}

// sc[p] = tafast[p] + u[i] + v[j] + P[i][j] + ba
__global__ void slow_gather(const float* __restrict__ P, const float* __restrict__ u,
                            const float* __restrict__ v, const int* __restrict__ ante,
                            const float* __restrict__ tafast, const float* __restrict__ ba,
                            float* sc, int m){
  int p = blockIdx.x*256 + threadIdx.x;
  if(p >= m*K2) return;
  int i = p / K2; int j = ante[p];
  sc[p] = tafast[p] + u[i] + v[j] + P[(size_t)i*m + j] + ba[0];
}

__global__ void attend_kernel(const float* __restrict__ reps, const float* __restrict__ sc,
                              const int* __restrict__ ante, float* att, int m){
  int i = blockIdx.x; int tid = threadIdx.x;
  __shared__ float wts[K2+1];
  __shared__ float scs[K2];
  __shared__ int   js[K2];
  if(tid < K2){ scs[tid] = sc[(size_t)i*K2 + tid]; js[tid] = ante[(size_t)i*K2 + tid]; }
  __syncthreads();
  if(tid==0){
    float mx = 0.f;
    for(int t=0;t<K2;t++) mx = fmaxf(mx, scs[t]);
    float sum = expf(0.f - mx); wts[0] = sum;
    for(int t=0;t<K2;t++){ float e = expf(scs[t]-mx); wts[t+1]=e; sum += e; }
    float inv = 1.f/sum;
    for(int t=0;t<=K2;t++) wts[t] *= inv;
  }
  __syncthreads();
  const float* ri_ = reps + (size_t)i*DD;
  for(int d=tid; d<DD; d+=256){
    float a = wts[0]*ri_[d];
    for(int t=0;t<K2;t++) a += wts[t+1]*reps[(size_t)js[t]*DD + d];
    att[(size_t)i*DD + d] = a;
  }
}

// ---------------- bf16 conversion for the fused gate GEMM -------------------
__global__ void conv_acat(const float* __restrict__ cur, const float* __restrict__ att,
                          unsigned short* __restrict__ A, int m){
  int idx = blockIdx.x*256 + threadIdx.x;
  if(idx >= MPAD*KAW) return;
  int row = idx / KAW, col = idx - row*KAW;
  float v = 0.f;
  if(row < m){
    if(col < DD) v = cur[(size_t)row*DD + col];
    else if(col >= KPAD && col < KPAD + DD) v = att[(size_t)row*DD + (col - KPAD)];
  }
  A[idx] = f2bf(v);
}

// Bt_cat (NPAD x KAW): Bt[n][s*KPAD+k] = Wf[s*DD+k][n], zero-padded
__global__ void conv_wf(const float* __restrict__ Wf, unsigned short* __restrict__ Bt){
  int n  = blockIdx.y*64 + threadIdx.x;
  int k8 = blockIdx.x*8;
  int s  = (k8 >= KPAD) ? 1 : 0;
  int kk = k8 - s*KPAD;
  u16x8 v;
  #pragma unroll
  for(int j=0;j<8;j++){
    int k = kk + j;
    float f = (n < DD && k < DD) ? Wf[(size_t)(s*DD + k)*DD + n] : 0.f;
    v[j] = f2bf(f);
  }
  *(u16x8*)(Bt + (size_t)n*KAW + k8) = v;
}

// ---------------- gate GEMM, split-K x4 (BK=64, atomic out) -----------------
// accumulates pre-activation (no bias) into Pre (= nxt buffer, pre-zeroed)
__global__ __launch_bounds__(256)
void wf_gate_gemm_sk(const unsigned short* __restrict__ Abuf,
                     const unsigned short* __restrict__ Bbuf,
                     float* __restrict__ Pre, int M){
  __shared__ __align__(16) unsigned short As[2][128*72];
  __shared__ __align__(16) unsigned short Bs[2][128*72];
  int t = threadIdx.x;
  int row0 = blockIdx.y*128, col0 = blockIdx.x*128;
  int tiles = KAW/64;                         // 76
  int per = tiles/4;                          // 19
  int kbeg = (int)blockIdx.z*per*64, kend = kbeg + per*64;
  int r4 = t>>2, seg = t&3;
  int lane = t&63, w = t>>6;
  int wr = (w>>1)*64, wc = (w&1)*64;
  int quad = lane>>4, l15 = lane&15;
  f32x4 acc[4][4];
  #pragma unroll
  for(int mi=0;mi<4;mi++)
    #pragma unroll
    for(int ni=0;ni<4;ni++) acc[mi][ni] = (f32x4){0.f,0.f,0.f,0.f};

  const unsigned short* Ap0 = Abuf + (size_t)(row0+r4   )*KAW + kbeg + seg*8;
  const unsigned short* Ap1 = Abuf + (size_t)(row0+r4+64)*KAW + kbeg + seg*8;
  const unsigned short* Bp0 = Bbuf + (size_t)(col0+r4   )*KAW + kbeg + seg*8;
  const unsigned short* Bp1 = Bbuf + (size_t)(col0+r4+64)*KAW + kbeg + seg*8;
  const int wlo = r4*72 + seg*8, whi = (r4+64)*72 + seg*8;

  u16x8 pa[2][2], pb[2][2];
  #pragma unroll
  for(int c=0;c<2;c++){
    pa[0][c]=*(const u16x8*)(Ap0+c*32); pa[1][c]=*(const u16x8*)(Ap1+c*32);
    pb[0][c]=*(const u16x8*)(Bp0+c*32); pb[1][c]=*(const u16x8*)(Bp1+c*32);
  }
  #pragma unroll
  for(int c=0;c<2;c++){
    *(u16x8*)&As[0][wlo+c*32]=pa[0][c]; *(u16x8*)&As[0][whi+c*32]=pa[1][c];
    *(u16x8*)&Bs[0][wlo+c*32]=pb[0][c]; *(u16x8*)&Bs[0][whi+c*32]=pb[1][c];
  }
  __syncthreads();
  int buf = 0;
  for(int k0=kbeg; k0<kend; k0+=64){
    int nk = k0 + 64;
    if(nk < kend){
      int off = nk - kbeg;
      #pragma unroll
      for(int c=0;c<2;c++){
        pa[0][c]=*(const u16x8*)(Ap0+off+c*32); pa[1][c]=*(const u16x8*)(Ap1+off+c*32);
        pb[0][c]=*(const u16x8*)(Bp0+off+c*32); pb[1][c]=*(const u16x8*)(Bp1+off+c*32);
      }
    }
    #pragma unroll
    for(int ks=0;ks<2;ks++){
      s8b fa[4], fb[4];
      #pragma unroll
      for(int mi=0;mi<4;mi++) fa[mi] = *(const s8b*)&As[buf][(wr+mi*16+l15)*72 + ks*32 + quad*8];
      #pragma unroll
      for(int ni=0;ni<4;ni++) fb[ni] = *(const s8b*)&Bs[buf][(wc+ni*16+l15)*72 + ks*32 + quad*8];
      #pragma unroll
      for(int mi=0;mi<4;mi++)
        #pragma unroll
        for(int ni=0;ni<4;ni++)
          acc[mi][ni] = __builtin_amdgcn_mfma_f32_16x16x32_bf16(fa[mi], fb[ni], acc[mi][ni], 0,0,0);
    }
    if(nk < kend){
      int nb = buf^1;
      #pragma unroll
      for(int c=0;c<2;c++){
        *(u16x8*)&As[nb][wlo+c*32]=pa[0][c]; *(u16x8*)&As[nb][whi+c*32]=pa[1][c];
        *(u16x8*)&Bs[nb][wlo+c*32]=pb[0][c]; *(u16x8*)&Bs[nb][whi+c*32]=pb[1][c];
      }
      __syncthreads();
      buf = nb;
    }
  }

  #pragma unroll
  for(int ni=0;ni<4;ni++){
    int gn = col0 + wc + ni*16 + l15;
    if(gn >= DD) continue;
    #pragma unroll
    for(int mi=0;mi<4;mi++){
      #pragma unroll
      for(int rg=0;rg<4;rg++){
        int gr = row0 + wr + mi*16 + quad*4 + rg;
        if(gr >= M) continue;
        atomicAdd(&Pre[(size_t)gr*DD + gn], acc[mi][ni][rg]);
      }
    }
  }
}

// gate epilogue: nxt holds accumulated pre-activation; apply bias+sigmoid+update
__global__ void gate_update(const float* __restrict__ bfv, const float* __restrict__ att,
                            const float* __restrict__ cur, float* __restrict__ nxt, int total){
  int idx = blockIdx.x*256 + threadIdx.x;
  if(idx >= total) return;
  int col = idx % DD;
  float pre = nxt[idx] + bfv[col];
  float g = 1.f/(1.f + expf(-pre));
  nxt[idx] = g*att[idx] + (1.f - g)*cur[idx];
}

// ---------------- final scores + per-row loss -------------------------------
__global__ void final_loss(const float* __restrict__ sc, const int* __restrict__ ante,
                           const int* __restrict__ tclust, float* out_fs, float* row_loss, int m){
  int i = blockIdx.x*blockDim.x + threadIdx.x;
  if(i >= m) return;
  int tci = tclust[i];
  unsigned long long labm = 0ull;
  bool anyp = false;
  float mx = 0.f;
  float mg = -FLT_MAX;
  for(int t=0;t<K2;t++){
    float v = sc[(size_t)i*K2 + t];
    mx = fmaxf(mx, v);
    int j = ante[(size_t)i*K2 + t];
    bool mk = (j < i);
    int ac = mk ? tclust[j] : -1;
    bool p = (ac == tci) && (tci > 0);
    if(p){ labm |= (1ull << (t+1)); anyp = true; mg = fmaxf(mg, v); }
  }
  if(!anyp){ labm |= 1ull; mg = 0.f; }
  float s1 = expf(0.f - mx);
  float s2 = (labm & 1ull) ? expf(0.f - mg) : 0.f;
  float* o = out_fs + (size_t)i*(K2+1);
  o[0] = 0.f;
  for(int t=0;t<K2;t++){
    float v = sc[(size_t)i*K2 + t];
    o[t+1] = v;
    s1 += expf(v - mx);
    if(labm & (1ull << (t+1))) s2 += expf(v - mg);
  }
  row_loss[i] = (mx + logf(s1)) - (mg + logf(s2));
}

__global__ void loss_sum(const float* __restrict__ row_loss, float* out, int m){
  int tid = threadIdx.x;
  float s = 0.f;
  for(int i=tid; i<m; i+=256) s += row_loss[i];
  __shared__ float red[256];
  red[tid]=s; __syncthreads();
  for(int st=128; st>0; st>>=1){ if(tid<st) red[tid]+=red[tid+st]; __syncthreads(); }
  if(tid==0) out[0] = red[0];
}

// ---------------------------------------------------------------------------
extern "C" void kernel_launch(void* const* d_in, const int* in_sizes, int n_in,
                              void* d_out, int out_size, void* d_ws, size_t ws_size,
                              hipStream_t stream){
  const int W = in_sizes[11];
  const int G = in_sizes[12];
  const int C = W * MSW;
  const int m = (int)(0.4 * (double)W);

  const float* seq   = (const float*)d_in[0];
  const float* Wal   = (const float*)d_in[1];
  const float* bal   = (const float*)d_in[2];
  const float* Wm    = (const float*)d_in[3];
  const float* bm    = (const float*)d_in[4];
  const float* Wc    = (const float*)d_in[5];
  const float* WaA   = (const float*)d_in[6];
  const float* baA   = (const float*)d_in[7];
  const float* Wf    = (const float*)d_in[8];
  const float* bf    = (const float*)d_in[9];
  const float* wfeat = (const float*)d_in[10];
  const int*   smap  = (const int*)d_in[11];
  const int*   gs    = (const int*)d_in[12];
  const int*   ge    = (const int*)d_in[13];
  const int*   cid   = (const int*)d_in[14];
  float* out = (float*)d_out;

  // workspace layout (phase-aliased; peak ~59 MB, proven safe <65 MB)
  char* ws = (char*)d_ws;
  size_t off = 0;
  auto alloc = [&](size_t bytes)->char*{
    char* p = ws + off;
    off += (bytes + 255) & ~(size_t)255;
    return p;
  };
  const size_t PLANE  = (size_t)MPAD*KPAD*2;   // 4.36 MB
  const size_t WPLANE = (size_t)NPAD*KPAD*2;   // 11.83 MB

  float* alphas  = (float*)alloc((size_t)W*4);
  float* p1      = (float*)alloc((size_t)W*4);
  float* p2      = (float*)alloc((size_t)W*4);
  float* p3      = (float*)alloc((size_t)W*4);
  float* mscore  = (float*)alloc((size_t)C*4);
  float* mmask   = (float*)alloc((size_t)C*4);
  int*   ccl     = (int*)  alloc((size_t)C*4);
  int*   top_idx = (int*)  alloc((size_t)m*4);
  float* tscore  = (float*)alloc((size_t)m*4);
  int*   tclust  = (int*)  alloc((size_t)m*4);
  float* B1      = (float*)alloc((size_t)m*DD*4);  // top_rep / reps ping
  float* B2      = (float*)alloc((size_t)m*DD*4);  // tmp / reps pong
  float* B3      = (float*)alloc((size_t)m*DD*4);  // attended
  float* bilin   = (float*)alloc((size_t)m*m*4);   // bilin, later P (slow matrix)
  int*   ante    = (int*)  alloc((size_t)m*K2*4);
  float* tafast  = (float*)alloc((size_t)m*K2*4);
  float* uB      = (float*)alloc((size_t)m*4);
  float* vB      = (float*)alloc((size_t)m*4);
  float* scB     = (float*)alloc((size_t)m*K2*4);
  float* rloss   = (float*)alloc((size_t)m*4);
  // regionA (2*PLANE), phase-aliased:
  //   bilinear: RepH | RepL      slow: XbfA | CurBf      gate: Acat (spans both)
  char* regionA = alloc(2*PLANE);
  unsigned short* RepH  = (unsigned short*)regionA;
  unsigned short* RepL  = (unsigned short*)(regionA + PLANE);
  unsigned short* XbfA  = (unsigned short*)regionA;
  unsigned short* CurBf = (unsigned short*)(regionA + PLANE);
  unsigned short* Acat  = (unsigned short*)regionA;            // MPAD*KAW*2 == 2*PLANE
  // regionB (2*WPLANE), phase-aliased:
  //   gemm1: WtH | WtL   ->  gemm2: A2H | A2L (after gemm1 done)  ->  depth: BtWf
  char* regionB = alloc(2*WPLANE);
  unsigned short* WtH  = (unsigned short*)regionB;
  unsigned short* WtL  = (unsigned short*)(regionB + WPLANE);
  unsigned short* A2H  = (unsigned short*)regionB;
  unsigned short* A2L  = (unsigned short*)(regionB + PLANE);
  unsigned short* BtWf = (unsigned short*)regionB;             // NPAD*KAW*2 == 2*WPLANE

  // output offsets (all float32)
  float* out_ts   = out;
  float* out_te   = out + m;
  float* out_ante = out + 2*m;
  float* out_fs   = out + 2*m + (size_t)m*K2;
  float* out_loss = out + 2*m + (size_t)m*K2 + (size_t)m*(K2+1);

  // 1) per-token projections
  row_proj<<<W, 256, 0, stream>>>(seq, Wal, bal, Wm, alphas, p1, p2, p3, W);
  // 2) candidate mention scores
  mention_kernel<<<(C+255)/256, 256, 0, stream>>>(alphas, p1, p2, p3, wfeat, Wm, bm,
                                                  smap, gs, ge, cid, G,
                                                  mscore, mmask, ccl, W);
  // 3) exact top-m selection + compaction
  select_kernel<<<1, 1024, 0, stream>>>(mmask, mscore, ccl, m, C, W,
                                        top_idx, tscore, tclust, out_ts, out_te);
  // 4) build top_rep into B1
  build_rep<<<m, 256, 0, stream>>>(seq, alphas, wfeat, top_idx, B1, W);
  // 5) bilinear antecedent scores via split-bf16 3-term MFMA (split-K x4, atomic)
  {
    const int NEL = MPAD*KPAD;
    conv_split<<<(NEL+255)/256, 256, 0, stream>>>(B1, m, DD, RepH, RepL);
    dim3 gw(KPAD/8, NPAD/64);
    conv_split_wcT<<<gw, 64, 0, stream>>>(Wc, WtH, WtL);
    zero_buf<<<(m*DD+255)/256, 256, 0, stream>>>(B2, m*DD);
    dim3 g1(NPAD/128, MPAD/128, 4);     // (19, 7, 4) = 532 blocks
    gemm_split3_sk<<<g1, 256, 0, stream>>>(RepH, RepL, WtH, WtL, B2, m, DD, DD);
    conv_split<<<(NEL+255)/256, 256, 0, stream>>>(B2, m, DD, A2H, A2L);
    zero_buf<<<(m*m+255)/256, 256, 0, stream>>>(bilin, m*m);
    dim3 g2(MPAD/128, MPAD/128, 4);     // (7, 7, 4) = 196 blocks
    gemm_split3_sk<<<g2, 256, 0, stream>>>(A2H, A2L, RepH, RepL, bilin, m, m, m);
  }
  // 6) per-row top-50 (1 wave per row)
  topante_kernel<<<m, 64, 0, stream>>>(tscore, bilin, m, ante, tafast, out_ante);
  // gate weights -> bf16 transposed (AFTER bilinear GEMMs: regionB alias)
  {
    dim3 g(KAW/8, NPAD/64);
    conv_wf<<<g, 64, 0, stream>>>(Wf, BtWf);
  }

  // 7) DEPTH=2 refinement (loss-path GEMMs: split-K x4 + atomic accumulate)
  float* cur = B1; float* nxt = B2;
  const int NEL = MPAD*KPAD;
  const int total = m * DD;
  for(int depth=0; depth<2; depth++){
    uv_kernel<<<m, 256, 0, stream>>>(cur, WaA, uB, vB, m);
    // slow scores: P = (cur .* w3) @ cur^T  (split-K x4, atomic into zeroed bilin)
    conv_slow_ops<<<(NEL+255)/256, 256, 0, stream>>>(cur, WaA, CurBf, XbfA, m);
    zero_buf<<<(m*m+255)/256, 256, 0, stream>>>(bilin, m*m);
    dim3 gp(MPAD/128, MPAD/128, 4);
    gemm_plain1_sk<<<gp, 256, 0, stream>>>(XbfA, CurBf, bilin, m, m, m);
    slow_gather<<<(m*K2+255)/256, 256, 0, stream>>>(bilin, uB, vB, ante, tafast, baA, scB, m);
    attend_kernel<<<m, 256, 0, stream>>>(cur, scB, ante, B3, m);
    // gate pre-activation accumulates into zeroed nxt; epilogue applied after
    conv_acat<<<(MPAD*KAW+255)/256, 256, 0, stream>>>(cur, B3, Acat, m);
    zero_buf<<<(total+255)/256, 256, 0, stream>>>(nxt, total);
    dim3 gg(NPAD/128, MPAD/128, 4);
    wf_gate_gemm_sk<<<gg, 256, 0, stream>>>(Acat, BtWf, nxt, m);
    gate_update<<<(total+255)/256, 256, 0, stream>>>(bf, B3, cur, nxt, total);
    float* t = cur; cur = nxt; nxt = t;
  }

  // 8) final scores + loss
  final_loss<<<(m+255)/256, 256, 0, stream>>>(scB, ante, tclust, out_fs, rloss, m);
  loss_sum<<<1, 256, 0, stream>>>(rloss, out_loss, m);
}